// Round 11
// baseline (1709.905 us; speedup 1.0000x reference)
//
#include <hip/hip_runtime.h>
#include <math.h>

#define T_TOKENS 2048
#define H_DIM 2048
#define E_NUM 64
#define I_DIM 768
#define TOPK 8
#define CAP 1024
#define TK (T_TOKENS * TOPK)
#define NTG (H_DIM / 32)   // 64 K-steps (gu)
#define NTD (I_DIM / 32)   // 24 K-steps (down)

typedef __attribute__((ext_vector_type(8))) short s8v;
typedef __attribute__((ext_vector_type(4))) float f32x4;

__device__ inline unsigned short f2bf(float f) {
    union { float f; unsigned int u; } v; v.f = f;
    return (unsigned short)((v.u + 0x7FFFu + ((v.u >> 16) & 1u)) >> 16);
}
__device__ inline unsigned int pack2(float lo, float hi) {
    unsigned int r;
    asm("v_cvt_pk_bf16_f32 %0, %1, %2" : "=v"(r) : "v"(lo), "v"(hi));
    return r;
}
// async global->LDS, 16B per lane; global addr per-lane, LDS dest = wave base + lane*16
__device__ inline void gload16(const void* g, void* l) {
    __builtin_amdgcn_global_load_lds((const __attribute__((address_space(1))) unsigned int*)g,
                                     (__attribute__((address_space(3))) unsigned int*)l, 16, 0, 0);
}

// ---------------- init counts ----------------
__global__ void init_cnt_kernel(int* __restrict__ cnt) {
    if (threadIdx.x < E_NUM) cnt[threadIdx.x] = 0;
}

// ---------------- zero output (atomic fallback path only) ----------------
__global__ __launch_bounds__(256) void zero_out_kernel(float* __restrict__ out, int n4) {
    int i = blockIdx.x * 256 + threadIdx.x;
    if (i < n4) reinterpret_cast<float4*>(out)[i] = make_float4(0.f, 0.f, 0.f, 0.f);
}

// ---------------- router: 4 tokens/block, fp32 logits (proven) + fused x->bf16 ----------------
__global__ __launch_bounds__(256) void router_kernel(const float* __restrict__ x,
                                                     const float* __restrict__ wr,
                                                     int* __restrict__ topi,
                                                     float* __restrict__ topw,
                                                     unsigned short* __restrict__ xbf) {
    __shared__ float xs[4][H_DIM];
    __shared__ float lg[4][E_NUM];
    int t0 = blockIdx.x * 4;
    int tid = threadIdx.x;
    #pragma unroll
    for (int r = 0; r < 4; ++r) {
        const float* xrow = x + (size_t)(t0 + r) * H_DIM + tid * 8;
        float4 a = *reinterpret_cast<const float4*>(xrow);
        float4 b = *reinterpret_cast<const float4*>(xrow + 4);
        *reinterpret_cast<float4*>(&xs[r][tid * 8])     = a;
        *reinterpret_cast<float4*>(&xs[r][tid * 8 + 4]) = b;
        int4 o;
        o.x = (int)pack2(a.x, a.y);
        o.y = (int)pack2(a.z, a.w);
        o.z = (int)pack2(b.x, b.y);
        o.w = (int)pack2(b.z, b.w);
        *reinterpret_cast<int4*>(xbf + (size_t)(t0 + r) * H_DIM + tid * 8) = o;
    }
    __syncthreads();
    int w = tid >> 6, lane = tid & 63;
    for (int eo = 0; eo < 16; ++eo) {
        int e = w * 16 + eo;
        const float* wrow = wr + (size_t)e * H_DIM;
        float a0 = 0.f, a1 = 0.f, a2 = 0.f, a3 = 0.f;
        for (int h = lane; h < H_DIM; h += 64) {
            float wv = wrow[h];
            a0 += wv * xs[0][h]; a1 += wv * xs[1][h];
            a2 += wv * xs[2][h]; a3 += wv * xs[3][h];
        }
        #pragma unroll
        for (int off = 32; off; off >>= 1) {
            a0 += __shfl_xor(a0, off); a1 += __shfl_xor(a1, off);
            a2 += __shfl_xor(a2, off); a3 += __shfl_xor(a3, off);
        }
        if (lane == 0) { lg[0][e] = a0; lg[1][e] = a1; lg[2][e] = a2; lg[3][e] = a3; }
    }
    __syncthreads();
    if (tid < 32) {
        int r = tid >> 3, rank = tid & 7;
        const float* lgr = lg[r];
        float pv = 3.4e38f; int pi = -1;
        float m = 0.f, s = 0.f, myv = 0.f; int myi = 0;
        for (int q = 0; q < TOPK; ++q) {
            float best = -3.4e38f; int bi = -1;
            for (int e2 = 0; e2 < E_NUM; ++e2) {
                float v = lgr[e2];
                bool excl = (v > pv) || (v == pv && e2 <= pi);
                if (!excl && v > best) { best = v; bi = e2; }
            }
            if (q == 0) m = best;
            s += expf(best - m);
            if (q == rank) { myv = best; myi = bi; }
            pv = best; pi = bi;
        }
        topw[(t0 + r) * TOPK + rank] = expf(myv - m) / s;
        topi[(t0 + r) * TOPK + rank] = myi;
    }
}

// ---------------- dispatch / offsets ----------------
__global__ __launch_bounds__(256) void dispatch_kernel(const int* __restrict__ topi,
                                                       int* __restrict__ cnt,
                                                       int* __restrict__ slot,
                                                       int* __restrict__ epos) {
    int i = blockIdx.x * 256 + threadIdx.x;
    int e = topi[i];
    int pos = atomicAdd(cnt + e, 1);
    epos[i] = pos;
    if (pos < CAP) slot[e * CAP + pos] = i;
}

__global__ void offs_kernel(const int* __restrict__ cnt, int* __restrict__ offs) {
    if (threadIdx.x == 0) {
        int run = 0;
        for (int e = 0; e < E_NUM; ++e) {
            offs[e] = run;
            int c = cnt[e]; if (c > CAP) c = CAP;
            run += c;
        }
    }
}

// ---------------- GEMM A (m97 schedule): 128 rows x (64g + 64u), BK=32, single-buffer ------
// A: gload_lds from xbf (k-contiguous bf16). B: reg-staged fp32 -> cvt -> ds_write.
__global__ __launch_bounds__(256, 4) void gemm_gu_kernel(const unsigned short* __restrict__ xbf,
                                                         const float* __restrict__ gup,
                                                         const int* __restrict__ slot,
                                                         const int* __restrict__ cnt,
                                                         const int* __restrict__ offs,
                                                         unsigned short* __restrict__ hws) {
    int e = blockIdx.z;
    int rows = min(cnt[e], CAP);
    int r0 = blockIdx.x * 128;
    if (r0 >= rows) return;
    int c0 = blockIdx.y * 64;            // gate col base; up col = I_DIM + c0
    int off_e = offs[e];

    __shared__ unsigned short As[128][32];   // linear: gload_lds dest (8 KB)
    __shared__ unsigned short Bs[128][40];   // padded: reg-staged   (10 KB)

    int tid = threadIdx.x;
    int w = tid >> 6, lane = tid & 63, l15 = lane & 15, grp = lane >> 4;

    // A stage: wave w covers rows w*32 .. w*32+31 (2 instrs, 16 rows each)
    const unsigned short* asrc[2];
    #pragma unroll
    for (int j = 0; j < 2; ++j) {
        int rloc = w * 32 + j * 16 + (lane >> 2);
        int rg = r0 + rloc;
        int ent = slot[e * CAP + min(rg, rows - 1)] >> 3;
        asrc[j] = xbf + (size_t)ent * H_DIM + (lane & 3) * 8;
    }
    // B stage: thread -> (colB, k-half)
    int colB = tid & 127, khalf = tid >> 7;
    int gcol = (colB < 64) ? (c0 + colB) : (I_DIM + c0 + (colB - 64));
    const float* bbase = gup + ((size_t)e * H_DIM + khalf * 16) * (2 * I_DIM) + gcol;

    f32x4 acc[2][8];
    #pragma unroll
    for (int m = 0; m < 2; ++m)
        #pragma unroll
        for (int f = 0; f < 8; ++f) acc[m][f] = (f32x4){0.f, 0.f, 0.f, 0.f};

    for (int t = 0; t < NTG; ++t) {
        int kk = t * 32;
        // stage: issue B global loads, A direct-to-LDS, then convert+write B
        float pb[16];
        #pragma unroll
        for (int j = 0; j < 16; ++j) pb[j] = bbase[(size_t)(kk + j) * (2 * I_DIM)];
        gload16(asrc[0] + kk, &As[w * 32][0]);
        gload16(asrc[1] + kk, &As[w * 32 + 16][0]);
        {
            unsigned int bw[8];
            #pragma unroll
            for (int j = 0; j < 8; ++j) bw[j] = pack2(pb[2 * j], pb[2 * j + 1]);
            *reinterpret_cast<int4*>(&Bs[colB][khalf * 16])     = make_int4(bw[0], bw[1], bw[2], bw[3]);
            *reinterpret_cast<int4*>(&Bs[colB][khalf * 16 + 8]) = make_int4(bw[4], bw[5], bw[6], bw[7]);
        }
        __syncthreads();   // stage visible (drains gload vmcnt + ds_write)
        // compute: wave w -> rows w*32..+31, all 128 colL
        s8v a0 = *reinterpret_cast<const s8v*>(&As[w * 32 + l15][grp * 8]);
        s8v a1 = *reinterpret_cast<const s8v*>(&As[w * 32 + 16 + l15][grp * 8]);
        #pragma unroll
        for (int f = 0; f < 8; ++f) {
            s8v b = *reinterpret_cast<const s8v*>(&Bs[f * 16 + l15][grp * 8]);
            acc[0][f] = __builtin_amdgcn_mfma_f32_16x16x32_bf16(a0, b, acc[0][f], 0, 0, 0);
            acc[1][f] = __builtin_amdgcn_mfma_f32_16x16x32_bf16(a1, b, acc[1][f], 0, 0, 0);
        }
        __syncthreads();   // LDS free for next stage
    }

    #pragma unroll
    for (int m = 0; m < 2; ++m) {
        #pragma unroll
        for (int f = 0; f < 4; ++f) {
            #pragma unroll
            for (int r = 0; r < 4; ++r) {
                int rg = r0 + w * 32 + m * 16 + grp * 4 + r;
                if (rg < rows) {
                    float g = acc[m][f][r];
                    float u = acc[m][f + 4][r];
                    float hv = (g / (1.f + expf(-g))) * u;
                    hws[(size_t)(off_e + rg) * I_DIM + (c0 + f * 16 + l15)] = f2bf(hv);
                }
            }
        }
    }
}

// ---------------- GEMM B (m97 schedule): 128 rows x 128 H-cols, BK=32, single-buffer ------
__global__ __launch_bounds__(256, 4) void gemm_down_kernel(const unsigned short* __restrict__ hws,
                                                           const float* __restrict__ dwn,
                                                           const int* __restrict__ slot,
                                                           const int* __restrict__ cnt,
                                                           const int* __restrict__ offs,
                                                           const float* __restrict__ topw,
                                                           float* __restrict__ out,
                                                           unsigned short* __restrict__ ye,
                                                           int use_ye) {
    int e = blockIdx.z;
    int rows = min(cnt[e], CAP);
    int r0 = blockIdx.x * 128;
    if (r0 >= rows) return;
    int c0 = blockIdx.y * 128;
    int off_e = offs[e];

    __shared__ unsigned short As[128][32];
    __shared__ unsigned short Bs[128][40];

    int tid = threadIdx.x;
    int w = tid >> 6, lane = tid & 63, l15 = lane & 15, grp = lane >> 4;

    const unsigned short* asrc[2];
    #pragma unroll
    for (int j = 0; j < 2; ++j) {
        int rloc = w * 32 + j * 16 + (lane >> 2);
        int rg = r0 + rloc;
        asrc[j] = hws + (size_t)(off_e + min(rg, rows - 1)) * I_DIM + (lane & 3) * 8;
    }
    int colB = tid & 127, khalf = tid >> 7;
    const float* bbase = dwn + ((size_t)e * I_DIM + khalf * 16) * H_DIM + c0 + colB;

    f32x4 acc[2][8];
    #pragma unroll
    for (int m = 0; m < 2; ++m)
        #pragma unroll
        for (int f = 0; f < 8; ++f) acc[m][f] = (f32x4){0.f, 0.f, 0.f, 0.f};

    for (int t = 0; t < NTD; ++t) {
        int kk = t * 32;
        float pb[16];
        #pragma unroll
        for (int j = 0; j < 16; ++j) pb[j] = bbase[(size_t)(kk + j) * H_DIM];
        gload16(asrc[0] + kk, &As[w * 32][0]);
        gload16(asrc[1] + kk, &As[w * 32 + 16][0]);
        {
            unsigned int bw[8];
            #pragma unroll
            for (int j = 0; j < 8; ++j) bw[j] = pack2(pb[2 * j], pb[2 * j + 1]);
            *reinterpret_cast<int4*>(&Bs[colB][khalf * 16])     = make_int4(bw[0], bw[1], bw[2], bw[3]);
            *reinterpret_cast<int4*>(&Bs[colB][khalf * 16 + 8]) = make_int4(bw[4], bw[5], bw[6], bw[7]);
        }
        __syncthreads();
        s8v a0 = *reinterpret_cast<const s8v*>(&As[w * 32 + l15][grp * 8]);
        s8v a1 = *reinterpret_cast<const s8v*>(&As[w * 32 + 16 + l15][grp * 8]);
        #pragma unroll
        for (int f = 0; f < 8; ++f) {
            s8v b = *reinterpret_cast<const s8v*>(&Bs[f * 16 + l15][grp * 8]);
            acc[0][f] = __builtin_amdgcn_mfma_f32_16x16x32_bf16(a0, b, acc[0][f], 0, 0, 0);
            acc[1][f] = __builtin_amdgcn_mfma_f32_16x16x32_bf16(a1, b, acc[1][f], 0, 0, 0);
        }
        __syncthreads();
    }

    if (use_ye) {
        #pragma unroll
        for (int m = 0; m < 2; ++m) {
            #pragma unroll
            for (int r = 0; r < 4; ++r) {
                int rg = r0 + w * 32 + m * 16 + grp * 4 + r;
                if (rg < rows) {
                    unsigned short* yrow = ye + (size_t)(off_e + rg) * H_DIM + c0 + l15;
                    #pragma unroll
                    for (int f = 0; f < 8; ++f)
                        yrow[f * 16] = f2bf(acc[m][f][r]);
                }
            }
        }
    } else {
        #pragma unroll
        for (int m = 0; m < 2; ++m) {
            #pragma unroll
            for (int r = 0; r < 4; ++r) {
                int rg = r0 + w * 32 + m * 16 + grp * 4 + r;
                if (rg < rows) {
                    int ent2 = slot[e * CAP + rg];
                    float wgt = topw[ent2];
                    float* obase = out + (size_t)(ent2 >> 3) * H_DIM + c0 + l15;
                    #pragma unroll
                    for (int f = 0; f < 8; ++f)
                        atomicAdd(obase + f * 16, wgt * acc[m][f][r]);
                }
            }
        }
    }
}

// ---------------- combine (ye path) ----------------
__global__ __launch_bounds__(256) void combine_kernel(const unsigned short* __restrict__ ye,
                                                      const int* __restrict__ topi,
                                                      const float* __restrict__ topw,
                                                      const int* __restrict__ epos,
                                                      const int* __restrict__ offs,
                                                      float* __restrict__ out) {
    int t = blockIdx.x;
    int tid = threadIdx.x;
    int base = t * TOPK;
    float acc[8];
    #pragma unroll
    for (int j = 0; j < 8; ++j) acc[j] = 0.f;
    #pragma unroll
    for (int k = 0; k < TOPK; ++k) {
        int e = topi[base + k];
        int p = epos[base + k];
        if (p < CAP) {
            int row = offs[e] + p;
            float wk = topw[base + k];
            int4 v = *reinterpret_cast<const int4*>(ye + (size_t)row * H_DIM + tid * 8);
            const unsigned short* vp = reinterpret_cast<const unsigned short*>(&v);
            #pragma unroll
            for (int j = 0; j < 8; ++j)
                acc[j] += wk * __uint_as_float(((unsigned int)vp[j]) << 16);
        }
    }
    float* orow = out + (size_t)t * H_DIM + tid * 8;
    *reinterpret_cast<float4*>(orow)     = make_float4(acc[0], acc[1], acc[2], acc[3]);
    *reinterpret_cast<float4*>(orow + 4) = make_float4(acc[4], acc[5], acc[6], acc[7]);
}

extern "C" void kernel_launch(void* const* d_in, const int* in_sizes, int n_in,
                              void* d_out, int out_size, void* d_ws, size_t ws_size,
                              hipStream_t stream) {
    const float* x   = (const float*)d_in[0];
    const float* wr  = (const float*)d_in[1];
    const float* gup = (const float*)d_in[2];
    const float* dwn = (const float*)d_in[3];
    float* out = (float*)d_out;
    char* ws = (char*)d_ws;

    int*            topi = (int*)(ws + 0);         //  64 KB
    float*          topw = (float*)(ws + 65536);   //  64 KB
    int*            cnt  = (int*)(ws + 131072);    // 256 B
    int*            offs = (int*)(ws + 131328);    // 256 B
    int*            epos = (int*)(ws + 131584);    //  64 KB
    int*            slot = (int*)(ws + 197120);    // 256 KB
    unsigned short* hws  = (unsigned short*)(ws + 459264);   // 24 MB
    unsigned short* xbf  = (unsigned short*)(ws + 33554432); //  8 MB
    unsigned short* ye   = (unsigned short*)(ws + 50331648); // 64 MB (ye path only)

    int use_ye = (ws_size >= (size_t)125829120) ? 1 : 0;

    init_cnt_kernel<<<1, 64, 0, stream>>>(cnt);
    if (!use_ye) {
        int n4 = out_size / 4;
        zero_out_kernel<<<(n4 + 255) / 256, 256, 0, stream>>>(out, n4);
    }
    router_kernel<<<T_TOKENS / 4, 256, 0, stream>>>(x, wr, topi, topw, xbf);
    dispatch_kernel<<<TK / 256, 256, 0, stream>>>(topi, cnt, slot, epos);
    offs_kernel<<<1, 64, 0, stream>>>(cnt, offs);
    gemm_gu_kernel<<<dim3(8, 12, E_NUM), 256, 0, stream>>>(xbf, gup, slot, cnt, offs, hws);
    gemm_down_kernel<<<dim3(8, 16, E_NUM), 256, 0, stream>>>(hws, dwn, slot, cnt, offs, topw, out, ye, use_ye);
    if (use_ye)
        combine_kernel<<<T_TOKENS, 256, 0, stream>>>(ye, topi, topw, epos, offs, out);
}

// Round 12
// 973.203 us; speedup vs baseline: 1.7570x; 1.7570x over previous
//
#include <hip/hip_runtime.h>
#include <math.h>

#define T_TOKENS 2048
#define H_DIM 2048
#define E_NUM 64
#define I_DIM 768
#define TOPK 8
#define CAP 1024
#define TK (T_TOKENS * TOPK)
#define RCHG 256           // rows per super-pass (4 x 64)
#define NTG (H_DIM / 32)   // 64 K-steps (gu), even
#define NTD (I_DIM / 32)   // 24 K-steps (down), even

typedef __attribute__((ext_vector_type(8))) short s8v;
typedef __attribute__((ext_vector_type(4))) float f32x4;

__device__ inline unsigned short f2bf(float f) {
    union { float f; unsigned int u; } v; v.f = f;
    return (unsigned short)((v.u + 0x7FFFu + ((v.u >> 16) & 1u)) >> 16);
}
__device__ inline unsigned int pack2(float lo, float hi) {
    unsigned int r;
    asm("v_cvt_pk_bf16_f32 %0, %1, %2" : "=v"(r) : "v"(lo), "v"(hi));
    return r;
}

// ---------------- init counts ----------------
__global__ void init_cnt_kernel(int* __restrict__ cnt) {
    if (threadIdx.x < E_NUM) cnt[threadIdx.x] = 0;
}

// ---------------- zero output (atomic fallback path only) ----------------
__global__ __launch_bounds__(256) void zero_out_kernel(float* __restrict__ out, int n4) {
    int i = blockIdx.x * 256 + threadIdx.x;
    if (i < n4) reinterpret_cast<float4*>(out)[i] = make_float4(0.f, 0.f, 0.f, 0.f);
}

// ---------------- router: 4 tokens/block, fp32 logits (proven) + fused x->bf16 ----------------
__global__ __launch_bounds__(256) void router_kernel(const float* __restrict__ x,
                                                     const float* __restrict__ wr,
                                                     int* __restrict__ topi,
                                                     float* __restrict__ topw,
                                                     unsigned short* __restrict__ xbf) {
    __shared__ float xs[4][H_DIM];
    __shared__ float lg[4][E_NUM];
    int t0 = blockIdx.x * 4;
    int tid = threadIdx.x;
    #pragma unroll
    for (int r = 0; r < 4; ++r) {
        const float* xrow = x + (size_t)(t0 + r) * H_DIM + tid * 8;
        float4 a = *reinterpret_cast<const float4*>(xrow);
        float4 b = *reinterpret_cast<const float4*>(xrow + 4);
        *reinterpret_cast<float4*>(&xs[r][tid * 8])     = a;
        *reinterpret_cast<float4*>(&xs[r][tid * 8 + 4]) = b;
        int4 o;
        o.x = (int)pack2(a.x, a.y);
        o.y = (int)pack2(a.z, a.w);
        o.z = (int)pack2(b.x, b.y);
        o.w = (int)pack2(b.z, b.w);
        *reinterpret_cast<int4*>(xbf + (size_t)(t0 + r) * H_DIM + tid * 8) = o;
    }
    __syncthreads();
    int w = tid >> 6, lane = tid & 63;
    for (int eo = 0; eo < 16; ++eo) {
        int e = w * 16 + eo;
        const float* wrow = wr + (size_t)e * H_DIM;
        float a0 = 0.f, a1 = 0.f, a2 = 0.f, a3 = 0.f;
        for (int h = lane; h < H_DIM; h += 64) {
            float wv = wrow[h];
            a0 += wv * xs[0][h]; a1 += wv * xs[1][h];
            a2 += wv * xs[2][h]; a3 += wv * xs[3][h];
        }
        #pragma unroll
        for (int off = 32; off; off >>= 1) {
            a0 += __shfl_xor(a0, off); a1 += __shfl_xor(a1, off);
            a2 += __shfl_xor(a2, off); a3 += __shfl_xor(a3, off);
        }
        if (lane == 0) { lg[0][e] = a0; lg[1][e] = a1; lg[2][e] = a2; lg[3][e] = a3; }
    }
    __syncthreads();
    if (tid < 32) {
        int r = tid >> 3, rank = tid & 7;
        const float* lgr = lg[r];
        float pv = 3.4e38f; int pi = -1;
        float m = 0.f, s = 0.f, myv = 0.f; int myi = 0;
        for (int q = 0; q < TOPK; ++q) {
            float best = -3.4e38f; int bi = -1;
            for (int e2 = 0; e2 < E_NUM; ++e2) {
                float v = lgr[e2];
                bool excl = (v > pv) || (v == pv && e2 <= pi);
                if (!excl && v > best) { best = v; bi = e2; }
            }
            if (q == 0) m = best;
            s += expf(best - m);
            if (q == rank) { myv = best; myi = bi; }
            pv = best; pi = bi;
        }
        topw[(t0 + r) * TOPK + rank] = expf(myv - m) / s;
        topi[(t0 + r) * TOPK + rank] = myi;
    }
}

// ---------------- dispatch / offsets ----------------
__global__ __launch_bounds__(256) void dispatch_kernel(const int* __restrict__ topi,
                                                       int* __restrict__ cnt,
                                                       int* __restrict__ slot,
                                                       int* __restrict__ epos) {
    int i = blockIdx.x * 256 + threadIdx.x;
    int e = topi[i];
    int pos = atomicAdd(cnt + e, 1);
    epos[i] = pos;
    if (pos < CAP) slot[e * CAP + pos] = i;
}

__global__ void offs_kernel(const int* __restrict__ cnt, int* __restrict__ offs) {
    if (threadIdx.x == 0) {
        int run = 0;
        for (int e = 0; e < E_NUM; ++e) {
            offs[e] = run;
            int c = cnt[e]; if (c > CAP) c = CAP;
            run += c;
        }
    }
}

// ---------------- GEMM A: (64-I-col strip, expert), rows internal, 2-deep float4 B-pipe ----
__global__ __launch_bounds__(256, 2) void gemm_gu_kernel(const unsigned short* __restrict__ xbf,
                                                         const float* __restrict__ gup,
                                                         const int* __restrict__ slot,
                                                         const int* __restrict__ cnt,
                                                         const int* __restrict__ offs,
                                                         unsigned short* __restrict__ hws) {
    int e = blockIdx.y;
    int rows = min(cnt[e], CAP);
    int c0 = blockIdx.x * 64;
    int off_e = offs[e];

    __shared__ unsigned short As[2][RCHG][40];
    __shared__ unsigned short Bt[2][128][40];

    int tid = threadIdx.x;
    int w = tid >> 6, lane = tid & 63, grp = lane >> 4, l15 = lane & 15;

    // B map: thread -> (col-quad cq: local cols 4cq..4cq+3, k-quad kq: ks 4kq..4kq+3)
    int cq = tid & 31, kq = tid >> 5;
    int L0 = 4 * cq;
    int gc0 = (L0 < 64) ? (c0 + L0) : (I_DIM + c0 + (L0 - 64));   // quads never straddle gate/up
    const float* bbase = gup + ((size_t)e * H_DIM + 4 * kq) * (2 * I_DIM) + gc0;

    int arow = tid >> 2, aq = tid & 3;

    for (int s0 = 0; s0 < rows; s0 += RCHG) {
        int nch = min(4, (rows - s0 + 63) >> 6);
        const unsigned short* ab[4];
        #pragma unroll
        for (int p = 0; p < 4; ++p) {
            int rg = s0 + p * 64 + arow;
            int ent = slot[e * CAP + min(rg, rows - 1)];
            ab[p] = xbf + (size_t)(ent >> 3) * H_DIM + aq * 8;
        }

        f32x4 acc[4][8];
        #pragma unroll
        for (int p = 0; p < 4; ++p)
            #pragma unroll
            for (int f = 0; f < 8; ++f) acc[p][f] = (f32x4){0.f, 0.f, 0.f, 0.f};

        float4 sB0[4], sB1[4];
        int4 pa[4];

#define LOADB(S, KK)                                                             \
        {                                                                        \
            _Pragma("unroll")                                                    \
            for (int j = 0; j < 4; ++j)                                          \
                S[j] = *reinterpret_cast<const float4*>(bbase + ((size_t)(KK) + j) * (2 * I_DIM)); \
        }
#define PACKB(B, S)                                                              \
        {                                                                        \
            _Pragma("unroll")                                                    \
            for (int i = 0; i < 4; ++i) {                                        \
                unsigned int w0 = pack2(S[0][i], S[1][i]);                       \
                unsigned int w1 = pack2(S[2][i], S[3][i]);                       \
                *reinterpret_cast<int2*>(&Bt[B][4 * cq + i][4 * kq]) = make_int2((int)w0, (int)w1); \
            }                                                                    \
        }
#define LOADA(KK)                                                                \
        {                                                                        \
            _Pragma("unroll")                                                    \
            for (int p = 0; p < 4; ++p)                                          \
                if (p < nch) pa[p] = *reinterpret_cast<const int4*>(ab[p] + (KK)); \
        }
#define PACKA(B)                                                                 \
        {                                                                        \
            _Pragma("unroll")                                                    \
            for (int p = 0; p < 4; ++p)                                          \
                if (p < nch) *reinterpret_cast<int4*>(&As[B][p * 64 + arow][aq * 8]) = pa[p]; \
        }
#define COMPUTE(B)                                                               \
        {                                                                        \
            s8v bf[8];                                                           \
            _Pragma("unroll")                                                    \
            for (int f = 0; f < 8; ++f)                                          \
                bf[f] = *reinterpret_cast<const s8v*>(&Bt[B][f * 16 + l15][grp * 8]); \
            _Pragma("unroll")                                                    \
            for (int p = 0; p < 4; ++p) {                                        \
                if (p < nch) {                                                   \
                    s8v a = *reinterpret_cast<const s8v*>(&As[B][p * 64 + w * 16 + l15][grp * 8]); \
                    _Pragma("unroll")                                            \
                    for (int f = 0; f < 8; ++f)                                  \
                        acc[p][f] = __builtin_amdgcn_mfma_f32_16x16x32_bf16(a, bf[f], acc[p][f], 0, 0, 0); \
                }                                                                \
            }                                                                    \
        }

        // prologue: tile0 packed to buf0; tile1 (B) in sB1; A(tile1) in pa
        LOADB(sB0, 0);
        LOADB(sB1, 32);
        LOADA(0);
        PACKB(0, sB0);
        PACKA(0);
        LOADA(32);
        __syncthreads();

        for (int tt = 0; tt < NTG; tt += 2) {
            if (tt + 2 < NTG) LOADB(sB0, (tt + 2) * 32);   // 2 steps ahead
            COMPUTE(0);                                     // tile tt
            if (tt + 1 < NTG) { PACKB(1, sB1); PACKA(1); }  // tile tt+1
            if (tt + 2 < NTG) LOADA((tt + 2) * 32);
            __syncthreads();
            if (tt + 3 < NTG) LOADB(sB1, (tt + 3) * 32);
            COMPUTE(1);                                     // tile tt+1
            if (tt + 2 < NTG) { PACKB(0, sB0); PACKA(0); }  // tile tt+2
            if (tt + 3 < NTG) LOADA((tt + 3) * 32);
            __syncthreads();
        }
#undef LOADB
#undef PACKB
#undef LOADA
#undef PACKA
#undef COMPUTE

        #pragma unroll
        for (int p = 0; p < 4; ++p) {
            if (p < nch) {
                #pragma unroll
                for (int f = 0; f < 4; ++f) {
                    #pragma unroll
                    for (int r = 0; r < 4; ++r) {
                        int rg = s0 + p * 64 + w * 16 + grp * 4 + r;
                        if (rg < rows) {
                            float g = acc[p][f][r];
                            float u = acc[p][f + 4][r];
                            float hv = (g / (1.f + expf(-g))) * u;
                            hws[(size_t)(off_e + rg) * I_DIM + (c0 + f * 16 + l15)] = f2bf(hv);
                        }
                    }
                }
            }
        }
    }
}

// ---------------- GEMM B: (128-H-col strip, expert), rows internal, 2-deep float4 B-pipe ----
__global__ __launch_bounds__(256, 2) void gemm_down_kernel(const unsigned short* __restrict__ hws,
                                                           const float* __restrict__ dwn,
                                                           const int* __restrict__ slot,
                                                           const int* __restrict__ cnt,
                                                           const int* __restrict__ offs,
                                                           const float* __restrict__ topw,
                                                           float* __restrict__ out,
                                                           unsigned short* __restrict__ ye,
                                                           int use_ye) {
    int e = blockIdx.y;
    int rows = min(cnt[e], CAP);
    int c0 = blockIdx.x * 128;
    int off_e = offs[e];

    __shared__ unsigned short As[2][RCHG][40];
    __shared__ unsigned short Bt[2][128][40];

    int tid = threadIdx.x;
    int w = tid >> 6, lane = tid & 63, grp = lane >> 4, l15 = lane & 15;

    int cq = tid & 31, kq = tid >> 5;
    const float* bbase = dwn + ((size_t)e * I_DIM + 4 * kq) * H_DIM + c0 + 4 * cq;

    int arow = tid >> 2, aq = tid & 3;

    for (int s0 = 0; s0 < rows; s0 += RCHG) {
        int nch = min(4, (rows - s0 + 63) >> 6);
        const unsigned short* ab[4];
        #pragma unroll
        for (int p = 0; p < 4; ++p) {
            int rg = s0 + p * 64 + arow;
            ab[p] = hws + (size_t)(off_e + min(rg, rows - 1)) * I_DIM + aq * 8;
        }

        f32x4 acc[4][8];
        #pragma unroll
        for (int p = 0; p < 4; ++p)
            #pragma unroll
            for (int f = 0; f < 8; ++f) acc[p][f] = (f32x4){0.f, 0.f, 0.f, 0.f};

        float4 sB0[4], sB1[4];
        int4 pa[4];

#define LOADB(S, KK)                                                             \
        {                                                                        \
            _Pragma("unroll")                                                    \
            for (int j = 0; j < 4; ++j)                                          \
                S[j] = *reinterpret_cast<const float4*>(bbase + ((size_t)(KK) + j) * H_DIM); \
        }
#define PACKB(B, S)                                                              \
        {                                                                        \
            _Pragma("unroll")                                                    \
            for (int i = 0; i < 4; ++i) {                                        \
                unsigned int w0 = pack2(S[0][i], S[1][i]);                       \
                unsigned int w1 = pack2(S[2][i], S[3][i]);                       \
                *reinterpret_cast<int2*>(&Bt[B][4 * cq + i][4 * kq]) = make_int2((int)w0, (int)w1); \
            }                                                                    \
        }
#define LOADA(KK)                                                                \
        {                                                                        \
            _Pragma("unroll")                                                    \
            for (int p = 0; p < 4; ++p)                                          \
                if (p < nch) pa[p] = *reinterpret_cast<const int4*>(ab[p] + (KK)); \
        }
#define PACKA(B)                                                                 \
        {                                                                        \
            _Pragma("unroll")                                                    \
            for (int p = 0; p < 4; ++p)                                          \
                if (p < nch) *reinterpret_cast<int4*>(&As[B][p * 64 + arow][aq * 8]) = pa[p]; \
        }
#define COMPUTE(B)                                                               \
        {                                                                        \
            s8v bf[8];                                                           \
            _Pragma("unroll")                                                    \
            for (int f = 0; f < 8; ++f)                                          \
                bf[f] = *reinterpret_cast<const s8v*>(&Bt[B][f * 16 + l15][grp * 8]); \
            _Pragma("unroll")                                                    \
            for (int p = 0; p < 4; ++p) {                                        \
                if (p < nch) {                                                   \
                    s8v a = *reinterpret_cast<const s8v*>(&As[B][p * 64 + w * 16 + l15][grp * 8]); \
                    _Pragma("unroll")                                            \
                    for (int f = 0; f < 8; ++f)                                  \
                        acc[p][f] = __builtin_amdgcn_mfma_f32_16x16x32_bf16(a, bf[f], acc[p][f], 0, 0, 0); \
                }                                                                \
            }                                                                    \
        }

        LOADB(sB0, 0);
        LOADB(sB1, 32);
        LOADA(0);
        PACKB(0, sB0);
        PACKA(0);
        LOADA(32);
        __syncthreads();

        for (int tt = 0; tt < NTD; tt += 2) {
            if (tt + 2 < NTD) LOADB(sB0, (tt + 2) * 32);
            COMPUTE(0);
            if (tt + 1 < NTD) { PACKB(1, sB1); PACKA(1); }
            if (tt + 2 < NTD) LOADA((tt + 2) * 32);
            __syncthreads();
            if (tt + 3 < NTD) LOADB(sB1, (tt + 3) * 32);
            COMPUTE(1);
            if (tt + 2 < NTD) { PACKB(0, sB0); PACKA(0); }
            if (tt + 3 < NTD) LOADA((tt + 3) * 32);
            __syncthreads();
        }
#undef LOADB
#undef PACKB
#undef LOADA
#undef PACKA
#undef COMPUTE

        if (use_ye) {
            #pragma unroll
            for (int p = 0; p < 4; ++p) {
                if (p < nch) {
                    #pragma unroll
                    for (int r = 0; r < 4; ++r) {
                        int rg = s0 + p * 64 + w * 16 + grp * 4 + r;
                        if (rg < rows) {
                            unsigned short* yrow = ye + (size_t)(off_e + rg) * H_DIM + c0 + l15;
                            #pragma unroll
                            for (int f = 0; f < 8; ++f)
                                yrow[f * 16] = f2bf(acc[p][f][r]);
                        }
                    }
                }
            }
        } else {
            #pragma unroll
            for (int p = 0; p < 4; ++p) {
                if (p < nch) {
                    #pragma unroll
                    for (int r = 0; r < 4; ++r) {
                        int rg = s0 + p * 64 + w * 16 + grp * 4 + r;
                        if (rg < rows) {
                            int ent2 = slot[e * CAP + rg];
                            float wgt = topw[ent2];
                            float* obase = out + (size_t)(ent2 >> 3) * H_DIM + c0 + l15;
                            #pragma unroll
                            for (int f = 0; f < 8; ++f)
                                atomicAdd(obase + f * 16, wgt * acc[p][f][r]);
                        }
                    }
                }
            }
        }
    }
}

// ---------------- combine (ye path) ----------------
__global__ __launch_bounds__(256) void combine_kernel(const unsigned short* __restrict__ ye,
                                                      const int* __restrict__ topi,
                                                      const float* __restrict__ topw,
                                                      const int* __restrict__ epos,
                                                      const int* __restrict__ offs,
                                                      float* __restrict__ out) {
    int t = blockIdx.x;
    int tid = threadIdx.x;
    int base = t * TOPK;
    float acc[8];
    #pragma unroll
    for (int j = 0; j < 8; ++j) acc[j] = 0.f;
    #pragma unroll
    for (int k = 0; k < TOPK; ++k) {
        int e = topi[base + k];
        int p = epos[base + k];
        if (p < CAP) {
            int row = offs[e] + p;
            float wk = topw[base + k];
            int4 v = *reinterpret_cast<const int4*>(ye + (size_t)row * H_DIM + tid * 8);
            const unsigned short* vp = reinterpret_cast<const unsigned short*>(&v);
            #pragma unroll
            for (int j = 0; j < 8; ++j)
                acc[j] += wk * __uint_as_float(((unsigned int)vp[j]) << 16);
        }
    }
    float* orow = out + (size_t)t * H_DIM + tid * 8;
    *reinterpret_cast<float4*>(orow)     = make_float4(acc[0], acc[1], acc[2], acc[3]);
    *reinterpret_cast<float4*>(orow + 4) = make_float4(acc[4], acc[5], acc[6], acc[7]);
}

extern "C" void kernel_launch(void* const* d_in, const int* in_sizes, int n_in,
                              void* d_out, int out_size, void* d_ws, size_t ws_size,
                              hipStream_t stream) {
    const float* x   = (const float*)d_in[0];
    const float* wr  = (const float*)d_in[1];
    const float* gup = (const float*)d_in[2];
    const float* dwn = (const float*)d_in[3];
    float* out = (float*)d_out;
    char* ws = (char*)d_ws;

    int*            topi = (int*)(ws + 0);         //  64 KB
    float*          topw = (float*)(ws + 65536);   //  64 KB
    int*            cnt  = (int*)(ws + 131072);    // 256 B
    int*            offs = (int*)(ws + 131328);    // 256 B
    int*            epos = (int*)(ws + 131584);    //  64 KB
    int*            slot = (int*)(ws + 197120);    // 256 KB
    unsigned short* hws  = (unsigned short*)(ws + 459264);   // 24 MB
    unsigned short* xbf  = (unsigned short*)(ws + 33554432); //  8 MB
    unsigned short* ye   = (unsigned short*)(ws + 50331648); // 64 MB (ye path only)

    int use_ye = (ws_size >= (size_t)125829120) ? 1 : 0;

    init_cnt_kernel<<<1, 64, 0, stream>>>(cnt);
    if (!use_ye) {
        int n4 = out_size / 4;
        zero_out_kernel<<<(n4 + 255) / 256, 256, 0, stream>>>(out, n4);
    }
    router_kernel<<<T_TOKENS / 4, 256, 0, stream>>>(x, wr, topi, topw, xbf);
    dispatch_kernel<<<TK / 256, 256, 0, stream>>>(topi, cnt, slot, epos);
    offs_kernel<<<1, 64, 0, stream>>>(cnt, offs);
    gemm_gu_kernel<<<dim3(12, 64), 256, 0, stream>>>(xbf, gup, slot, cnt, offs, hws);
    gemm_down_kernel<<<dim3(16, 64), 256, 0, stream>>>(hws, dwn, slot, cnt, offs, topw, out, ye, use_ye);
    if (use_ye)
        combine_kernel<<<T_TOKENS, 256, 0, stream>>>(ye, topi, topw, epos, offs, out);
}